// Round 5
// baseline (329.801 us; speedup 1.0000x reference)
//
#include <hip/hip_runtime.h>
#include <hip/hip_bf16.h>

// VariableSelectionNetwork (TFT VSN) fused kernel for MI355X / gfx950.
// B=64 T=512 F=32 U=64, rows N = B*T = 32768.
// out = concat( out[N][64], w[N][32] ) in f32.
//
// R4: transposed GEMM1 (mfma(W2^T, h1)) -> h2 lands in-register in exactly the
// lane layout GEMM2's A-fragment needs (custom k-slot convention baked into
// Wg1/Wg2 B-fragments by prep). No LDS roundtrip, no lgkmcnt(0) drain.
// RPB=16, f-split-4 (8 f per wave), grid 2048 = 8 blocks/CU = 32 waves/CU.
// LDS 19968 B; launch_bounds(256,8) targets VGPR<=64.

typedef float f4      __attribute__((ext_vector_type(4)));
typedef float f2      __attribute__((ext_vector_type(2)));
typedef float f32x4   __attribute__((ext_vector_type(4)));
typedef short bf16x8  __attribute__((ext_vector_type(8)));
typedef unsigned short u16x8 __attribute__((ext_vector_type(8)));

#define N_ROWS 32768
#define F_DIM  32
#define U_DIM  64
#define RPB    16
#define NTHR   256
#define NBLK   (N_ROWS / RPB)   // 2048

// ---- LDS layout (total 19968 B; 8 blocks/CU = 156 KiB) ----
#define X_OFF   0        // f32[16][36] x tile                      (2304)
#define WT_OFF  2304     // u16[16][40] softmax weights bf16        (1280)
#define PW_OFF  3584     // phase A: f32[2][1024] weight stage (8192)
                         // phase B: vst f32[4][576] (9216)
                         // finale : cmb f32[4][1024] (16384)
#define VA_OFF  11776    // f32[6][32] phase-A vectors              (768)
#define HX_OFF  12544    // f32[16][36] phase-A hidden              (2304)
#define SMEM_BYTES 19968

__device__ __forceinline__ unsigned short bfu(float x) {
  union { __hip_bfloat16 h; unsigned short u; } c;
  c.h = __float2bfloat16(x);
  return c.u;
}
__device__ __forceinline__ float bf2f(unsigned short u) {
  union { float f; unsigned v; } c; c.v = ((unsigned)u) << 16; return c.f;
}

// =====================================================================
// prep:
//  m=0: W2 as A-fragments for transposed GEMM1:
//       chunk c = nt*128+kt*64+lane ; val[j] = W2[f][8g+32kt+j][lr+16nt]
//  m=1,2: Wg1/Wg2 as B-fragments with custom k-order:
//       val[j] = W[f][4g+(j&3)+16*(j>>2)+32kt][lr+16nt]
//  vect[f][576] = [W1(64) | b1(64) | b2(64) | Q: (bg1,bg2,Wp,bp)[u] (256) |
//                  G: (gamma,beta)[u] (128)]
// =====================================================================
__global__ __launch_bounds__(256) void vsn_prep(
    const float* __restrict__ W2,  const float* __restrict__ Wg1, const float* __restrict__ Wg2,
    const float* __restrict__ W1,  const float* __restrict__ b1,  const float* __restrict__ b2,
    const float* __restrict__ bg1, const float* __restrict__ bg2,
    const float* __restrict__ Wp,  const float* __restrict__ bp,
    const float* __restrict__ gamma_, const float* __restrict__ beta_,
    unsigned short* __restrict__ wtg, float* __restrict__ vect)
{
  const int t = threadIdx.x, blk = blockIdx.x;
  if (blk < 192) {
    const int m = blk >> 6;              // 0..2
    const int f = (blk >> 1) & 31;
    const int half = blk & 1;
    const float* src = (m == 0) ? W2 : (m == 1) ? Wg1 : Wg2;
    src += f * 4096;
    const int c  = half * 256 + t;       // chunk 0..511
    const int nt = c >> 7;
    const int rr = c & 127;
    const int kt = rr >> 6;
    const int ln = rr & 63;
    const int g  = ln >> 4, lrr = ln & 15;
    const int uo = lrr + 16 * nt;
    u16x8 tmp;
    if (m == 0) {
      #pragma unroll
      for (int j = 0; j < 8; ++j)
        tmp[j] = bfu(src[(8 * g + 32 * kt + j) * 64 + uo]);
    } else {
      #pragma unroll
      for (int j = 0; j < 8; ++j)
        tmp[j] = bfu(src[(4 * g + (j & 3) + 16 * (j >> 2) + 32 * kt) * 64 + uo]);
    }
    *(u16x8*)(wtg + ((size_t)(m * 32 + f) * 512 + c) * 8) = tmp;
  } else {
    const int h = blk - 192;             // 0..1
    for (int i = h * 1024 + t; i < (h + 1) * 1024; i += 256) {
      const int f = i >> 6, u = i & 63;
      float* vf = vect + f * 576;
      vf[u]              = W1[i];
      vf[64 + u]         = b1[i];
      vf[128 + u]        = b2[i];
      vf[192 + u * 4 + 0] = bg1[i];
      vf[192 + u * 4 + 1] = bg2[i];
      vf[192 + u * 4 + 2] = Wp[i];
      vf[192 + u * 4 + 3] = bp[i];
      vf[448 + u * 2 + 0] = gamma_[i];
      vf[448 + u * 2 + 1] = beta_[i];
    }
  }
}

// =====================================================================
// main fused kernel
// =====================================================================
__global__ __launch_bounds__(NTHR, 8) void vsn_main(
    const float* __restrict__ x,
    const unsigned short* __restrict__ wtg,
    const float* __restrict__ vect,
    const float* __restrict__ w1w, const float* __restrict__ w2w,
    const float* __restrict__ wg1w, const float* __restrict__ wg2w,
    const float* __restrict__ b1w, const float* __restrict__ b2w,
    const float* __restrict__ bg1w, const float* __restrict__ bg2w,
    const float* __restrict__ gammaw, const float* __restrict__ betaw,
    float* __restrict__ out, float* __restrict__ wout)
{
  __shared__ __align__(16) char smem[SMEM_BYTES];
  const int t  = threadIdx.x;
  const int r0 = blockIdx.x * RPB;

  float* xt  = (float*)(smem + X_OFF);                      // [16][36] f32
  unsigned short* wtlb = (unsigned short*)(smem + WT_OFF);  // [16][40] bf16
  float* wA  = (float*)(smem + PW_OFF);                     // phase A stage
  float* vAl = (float*)(smem + VA_OFF);
  float* hex = (float*)(smem + HX_OFF);

  const int wid  = t >> 6;            // wave 0..3 -> f-quarter
  const int lane = t & 63;
  const int lr   = lane & 15;
  const int lg   = lane >> 4;
  const int fbase = wid * 8;

  // ---- stage x tile: 16 rows x 32 f = 128 f4 ----
  if (t < 128) {
    f4 v = ((const f4*)(x + (size_t)r0 * F_DIM))[t];
    *((f4*)(xt + (t >> 3) * 36 + ((t & 7) << 2))) = v;
  }

  // ---- prefetch f=fbase vect into regs (held through phase A) ----
  const f4* vect4 = (const f4*)vect;
  f4 rv0 = vect4[fbase * 144 + lane];
  f4 rv1 = vect4[fbase * 144 + 64 + lane];
  f4 rv2 = {};
  if (lane < 16) rv2 = vect4[fbase * 144 + 128 + lane];

  // ---- stage phase-A weights: w1w, w2w ----
  #pragma unroll
  for (int i = 0; i < 2; ++i) {
    int i4 = t + i * NTHR;                   // 0..511
    int m = i4 >> 8, off = (i4 & 255) << 2;
    const float* src = m ? w2w : w1w;
    *(f4*)(wA + m * 1024 + off) = *((const f4*)(src + off));
  }
  if (t < 48) {
    int m = t >> 3, off = (t & 7) << 2;
    const float* src = (m==0)?b1w:(m==1)?b2w:(m==2)?bg1w:(m==3)?bg2w:(m==4)?gammaw:betaw;
    *(f4*)(vAl + m * 32 + off) = *((const f4*)(src + off));
  }
  __syncthreads();

  // ================= PHASE A : weights GRN + softmax =================
  {
    const int ar = t >> 4;        // row 0..15
    const int g0 = (t & 15) << 1; // 2 output cols

    // stage 1: h1 = elu(x @ w1w + b1w)
    f2 hacc = { vAl[g0], vAl[g0 + 1] };
    #pragma unroll
    for (int ff = 0; ff < 32; ++ff) {
      float xv = xt[ar * 36 + ff];
      f2 w0 = *(const f2*)(wA + ff * 32 + g0);
      hacc.x += xv * w0.x; hacc.y += xv * w0.y;
    }
    hacc.x = hacc.x > 0.f ? hacc.x : (__expf(hacc.x) - 1.f);
    hacc.y = hacc.y > 0.f ? hacc.y : (__expf(hacc.y) - 1.f);
    *(f2*)(hex + ar * 36 + g0) = hacc;
    __syncthreads();

    // stage 2: h2 = h1 @ w2w + b2w
    f2 h2acc = { vAl[32 + g0], vAl[32 + g0 + 1] };
    #pragma unroll
    for (int ff = 0; ff < 32; ++ff) {
      float hv = hex[ar * 36 + ff];
      f2 w0 = *(const f2*)(wA + 1024 + ff * 32 + g0);
      h2acc.x += hv * w0.x; h2acc.y += hv * w0.y;
    }
    __syncthreads();   // h1 reads done; wA(w1w/w2w) reads done
    *(f2*)(hex + ar * 36 + g0) = h2acc;
    // restage wg1w, wg2w over wA
    #pragma unroll
    for (int i = 0; i < 2; ++i) {
      int i4 = t + i * NTHR;
      int m = i4 >> 8, off = (i4 & 255) << 2;
      const float* src = m ? wg2w : wg1w;
      *(f4*)(wA + m * 1024 + off) = *((const f4*)(src + off));
    }
    __syncthreads();

    // stage 3: GLU
    f2 aacc = { vAl[64 + g0], vAl[64 + g0 + 1] };
    f2 bacc = { vAl[96 + g0], vAl[96 + g0 + 1] };
    #pragma unroll
    for (int ff = 0; ff < 32; ++ff) {
      float hv = hex[ar * 36 + ff];
      f2 wa0 = *(const f2*)(wA + ff * 32 + g0);
      f2 wb0 = *(const f2*)(wA + 1024 + ff * 32 + g0);
      aacc.x += hv * wa0.x; aacc.y += hv * wa0.y;
      bacc.x += hv * wb0.x; bacc.y += hv * wb0.y;
    }
    f2 zz;
    {
      float sgx = __builtin_amdgcn_rcpf(1.f + __expf(-bacc.x));
      float sgy = __builtin_amdgcn_rcpf(1.f + __expf(-bacc.y));
      zz.x = aacc.x * sgx + xt[ar * 36 + g0];
      zz.y = aacc.y * sgy + xt[ar * 36 + g0 + 1];
    }
    __syncthreads();   // h2 reads done
    *(f2*)(hex + ar * 36 + g0) = zz;
    __syncthreads();

    // LN + softmax over F=32
    float s1 = 0.f, s2 = 0.f;
    #pragma unroll
    for (int ff = 0; ff < 32; ++ff) { float z = hex[ar * 36 + ff]; s1 += z; s2 += z * z; }
    float mA = s1 * 0.03125f;
    float vA = s2 * 0.03125f - mA * mA;
    float rsA = __builtin_amdgcn_rsqf(vA + 1e-3f);
    float mx = -1e30f;
    #pragma unroll
    for (int ff = 0; ff < 32; ++ff) {
      float y = (hex[ar * 36 + ff] - mA) * rsA * vAl[128 + ff] + vAl[160 + ff];
      mx = fmaxf(mx, y);
    }
    float es = 0.f;
    #pragma unroll
    for (int ff = 0; ff < 32; ++ff) {
      float y = (hex[ar * 36 + ff] - mA) * rsA * vAl[128 + ff] + vAl[160 + ff];
      es += __expf(y - mx);
    }
    float inv = __builtin_amdgcn_rcpf(es);
    float w0 = __expf((hex[ar * 36 + g0] - mA) * rsA * vAl[128 + g0] + vAl[160 + g0] - mx) * inv;
    float w1_ = __expf((hex[ar * 36 + g0 + 1] - mA) * rsA * vAl[128 + g0 + 1] + vAl[160 + g0 + 1] - mx) * inv;
    unsigned wu = (unsigned)bfu(w0) | ((unsigned)bfu(w1_) << 16);
    *(unsigned*)(wtlb + ar * 40 + g0) = wu;
    *(f2*)(wout + (size_t)(r0 + ar) * 32 + g0) = (f2){w0, w1_};
    __syncthreads();   // phase A done; PW region free for vst
  }

  // ================= PHASE B : per-feature GRNs (MFMA, barrier-free) ====
  f4* vst4 = ((f4*)(smem + PW_OFF)) + wid * 144;   // wave-private 576 f32
  float* vsc = (float*)(smem + PW_OFF) + wid * 576;

  vst4[lane] = rv0; vst4[64 + lane] = rv1;
  if (lane < 16) vst4[128 + lane] = rv2;

  const bf16x8* wf = (const bf16x8*)wtg;

  f32x4 acc[4];
  #pragma unroll
  for (int nt = 0; nt < 4; ++nt) acc[nt] = (f32x4){0.f, 0.f, 0.f, 0.f};

  for (int i = 0; i < 8; ++i) {
    const int f = fbase + i;

    // ---- GEMM1 A-operand: W2^T fragments (8 coalesced 16B from L2) ----
    const int base0 = (0 * 32 + f) * 512 + lane;
    bf16x8 w2f[8];
    #pragma unroll
    for (int nt = 0; nt < 4; ++nt)
      #pragma unroll
      for (int kt = 0; kt < 2; ++kt)
        w2f[nt * 2 + kt] = wf[base0 + nt * 128 + kt * 64];

    // ---- h1 B-fragments (batch row = lr), rank-1 + ELU ----
    const float s_ = xt[lr * 36 + f];
    bf16x8 afr[2];
    #pragma unroll
    for (int kt = 0; kt < 2; ++kt) {
      const int u0 = 8 * lg + 32 * kt;
      f4 wa  = *(const f4*)(vsc + u0);
      f4 wb_ = *(const f4*)(vsc + u0 + 4);
      f4 ba  = *(const f4*)(vsc + 64 + u0);
      f4 bb_ = *(const f4*)(vsc + 64 + u0 + 4);
      bf16x8 af;
      #pragma unroll
      for (int j = 0; j < 4; ++j) {
        float h = s_ * wa[j] + ba[j];
        h = h > 0.f ? h : (__expf(h) - 1.f);
        af[j] = (short)bfu(h);
      }
      #pragma unroll
      for (int j = 0; j < 4; ++j) {
        float h = s_ * wb_[j] + bb_[j];
        h = h > 0.f ? h : (__expf(h) - 1.f);
        af[4 + j] = (short)bfu(h);
      }
      afr[kt] = af;
    }

    // ---- transposed GEMM1: c1[nt'] = h2^T block (rows=u, cols=batch) ----
    f32x4 c1[4];
    #pragma unroll
    for (int nt = 0; nt < 4; ++nt) {
      c1[nt] = (f32x4){0.f, 0.f, 0.f, 0.f};
      #pragma unroll
      for (int kt = 0; kt < 2; ++kt)
        c1[nt] = __builtin_amdgcn_mfma_f32_16x16x32_bf16(w2f[nt * 2 + kt], afr[kt], c1[nt], 0, 0, 0);
    }

    // ---- a2 fragments assembled in registers: lane holds its own row ----
    f4 b2q[4];
    #pragma unroll
    for (int kt = 0; kt < 2; ++kt)
      #pragma unroll
      for (int n2 = 0; n2 < 2; ++n2)
        b2q[n2 + 2 * kt] = *(const f4*)(vsc + 128 + 4 * lg + 16 * n2 + 32 * kt);
    bf16x8 a2[2];
    #pragma unroll
    for (int kt = 0; kt < 2; ++kt) {
      bf16x8 af;
      #pragma unroll
      for (int j = 0; j < 8; ++j) {
        const int q = (j >> 2) + 2 * kt;
        af[j] = (short)bfu(c1[q][j & 3] + b2q[q][j & 3]);
      }
      a2[kt] = af;
    }

    // ---- GEMM2a ----
    const int base1 = (1 * 32 + f) * 512 + lane;
    bf16x8 bfa[8];
    #pragma unroll
    for (int nt = 0; nt < 4; ++nt)
      #pragma unroll
      for (int kt = 0; kt < 2; ++kt)
        bfa[nt * 2 + kt] = wf[base1 + nt * 128 + kt * 64];
    f32x4 ca[4], cb[4];
    #pragma unroll
    for (int nt = 0; nt < 4; ++nt) {
      ca[nt] = (f32x4){0.f,0.f,0.f,0.f};
      #pragma unroll
      for (int kt = 0; kt < 2; ++kt)
        ca[nt] = __builtin_amdgcn_mfma_f32_16x16x32_bf16(a2[kt], bfa[nt * 2 + kt], ca[nt], 0, 0, 0);
    }

    // ---- GEMM2b ----
    const int base2 = (2 * 32 + f) * 512 + lane;
    bf16x8 bfb[8];
    #pragma unroll
    for (int nt = 0; nt < 4; ++nt)
      #pragma unroll
      for (int kt = 0; kt < 2; ++kt)
        bfb[nt * 2 + kt] = wf[base2 + nt * 128 + kt * 64];
    #pragma unroll
    for (int nt = 0; nt < 4; ++nt) {
      cb[nt] = (f32x4){0.f,0.f,0.f,0.f};
      #pragma unroll
      for (int kt = 0; kt < 2; ++kt)
        cb[nt] = __builtin_amdgcn_mfma_f32_16x16x32_bf16(a2[kt], bfb[nt * 2 + kt], cb[nt], 0, 0, 0);
    }

    // ---- prefetch vect f+1 ----
    if (i < 7) {
      rv0 = vect4[(f + 1) * 144 + lane];
      rv1 = vect4[(f + 1) * 144 + 64 + lane];
      if (lane < 16) rv2 = vect4[(f + 1) * 144 + 128 + lane];
    }

    // ---- epilogue: GLU + residual + LN + weighted accumulate ----
    float xr[4], wr[4];
    #pragma unroll
    for (int rg = 0; rg < 4; ++rg) {
      const int rl = 4 * lg + rg;
      xr[rg] = xt[rl * 36 + f];
      wr[rg] = bf2f(wtlb[rl * 40 + f]);
    }
    float zf[4][4];
    float s1[4] = {0.f,0.f,0.f,0.f}, s2[4] = {0.f,0.f,0.f,0.f};
    #pragma unroll
    for (int nt = 0; nt < 4; ++nt) {
      const int u = lr + 16 * nt;
      f4 Q = *(const f4*)(vsc + 192 + u * 4);   // bg1, bg2, Wp, bp
      #pragma unroll
      for (int rg = 0; rg < 4; ++rg) {
        float a = ca[nt][rg] + Q[0];
        float b = cb[nt][rg] + Q[1];
        float sg = __builtin_amdgcn_rcpf(1.f + __expf(-b));
        float z = a * sg + (xr[rg] * Q[2] + Q[3]);
        zf[nt][rg] = z;
        s1[rg] += z;
        s2[rg] += z * z;
      }
    }
    #pragma unroll
    for (int rg = 0; rg < 4; ++rg) {
      #pragma unroll
      for (int m = 1; m < 16; m <<= 1) {
        s1[rg] += __shfl_xor(s1[rg], m, 64);
        s2[rg] += __shfl_xor(s2[rg], m, 64);
      }
    }
    float rswr[4], nc2[4];
    #pragma unroll
    for (int rg = 0; rg < 4; ++rg) {
      float mn = s1[rg] * 0.015625f;
      float var = s2[rg] * 0.015625f - mn * mn;
      float rs = __builtin_amdgcn_rsqf(var + 1e-3f);
      rswr[rg] = rs * wr[rg];
      nc2[rg]  = -mn * rswr[rg];
    }
    #pragma unroll
    for (int nt = 0; nt < 4; ++nt) {
      const int u = lr + 16 * nt;
      f2 G = *(const f2*)(vsc + 448 + u * 2);   // gamma, beta
      #pragma unroll
      for (int rg = 0; rg < 4; ++rg) {
        float tm = rswr[rg] * zf[nt][rg] + nc2[rg];
        acc[nt][rg] += G.x * tm + G.y * wr[rg];
      }
    }

    // ---- write f+1 vect to wave-private LDS (in-order DS, no barrier) ----
    if (i < 7) {
      vst4[lane] = rv0; vst4[64 + lane] = rv1;
      if (lane < 16) vst4[128 + lane] = rv2;
    }
  }

  // ---- combine the 4 f-quarters and store ----
  __syncthreads();    // all vst reads done; PW region free for cmb
  float* cmb = (float*)(smem + PW_OFF);
  #pragma unroll
  for (int nt = 0; nt < 4; ++nt)
    #pragma unroll
    for (int rg = 0; rg < 4; ++rg)
      cmb[wid * 1024 + (4 * lg + rg) * 64 + lr + 16 * nt] = acc[nt][rg];
  __syncthreads();
  {
    const f4* cmb4 = (const f4*)cmb;
    f4 o = cmb4[t] + cmb4[256 + t] + cmb4[512 + t] + cmb4[768 + t];
    ((f4*)(out + (size_t)r0 * U_DIM))[t] = o;
  }
}

// =====================================================================
extern "C" void kernel_launch(void* const* d_in, const int* in_sizes, int n_in,
                              void* d_out, int out_size, void* d_ws, size_t ws_size,
                              hipStream_t stream)
{
  (void)in_sizes; (void)n_in; (void)out_size; (void)ws_size;
  const float* x    = (const float*)d_in[0];
  const float* W1   = (const float*)d_in[1];
  const float* b1   = (const float*)d_in[2];
  const float* W2   = (const float*)d_in[3];
  const float* b2   = (const float*)d_in[4];
  const float* Wg1  = (const float*)d_in[5];
  const float* bg1  = (const float*)d_in[6];
  const float* Wg2  = (const float*)d_in[7];
  const float* bg2  = (const float*)d_in[8];
  const float* Wp   = (const float*)d_in[9];
  const float* bp   = (const float*)d_in[10];
  const float* gm   = (const float*)d_in[11];
  const float* bt   = (const float*)d_in[12];
  const float* w1w  = (const float*)d_in[13];
  const float* b1w  = (const float*)d_in[14];
  const float* w2w  = (const float*)d_in[15];
  const float* b2w  = (const float*)d_in[16];
  const float* wg1w = (const float*)d_in[17];
  const float* bg1w = (const float*)d_in[18];
  const float* wg2w = (const float*)d_in[19];
  const float* bg2w = (const float*)d_in[20];
  const float* gmw  = (const float*)d_in[21];
  const float* btw  = (const float*)d_in[22];

  unsigned short* wtg = (unsigned short*)d_ws;             // 786432 B
  float* vect = (float*)((char*)d_ws + 786432);            // 73728 B

  float* out  = (float*)d_out;
  float* wout = out + (size_t)N_ROWS * U_DIM;

  vsn_prep<<<194, 256, 0, stream>>>(W2, Wg1, Wg2, W1, b1, b2, bg1, bg2, Wp, bp, gm, bt, wtg, vect);
  vsn_main<<<NBLK, NTHR, 0, stream>>>(x, wtg, vect, w1w, w2w, wg1w, wg2w,
                                      b1w, b2w, bg1w, bg2w, gmw, btw, out, wout);
}

// Round 6
// 197.492 us; speedup vs baseline: 1.6700x; 1.6700x over previous
//
#include <hip/hip_runtime.h>
#include <hip/hip_bf16.h>

// VariableSelectionNetwork (TFT VSN) fused kernel for MI355X / gfx950.
// B=64 T=512 F=32 U=64, rows N = B*T = 32768.
// out = concat( out[N][64], w[N][32] ) in f32.
//
// R5: R4 structure (transposed GEMM1, in-register h2->a2 handoff, barrier-free
// f-loop) with launch_bounds(256,4): R4's (256,8) capped VGPR at 32 and spilled
// 930MB/dispatch to scratch (FETCH 368MB). 128-VGPR cap, 16 waves/CU.

typedef float f4      __attribute__((ext_vector_type(4)));
typedef float f2      __attribute__((ext_vector_type(2)));
typedef float f32x4   __attribute__((ext_vector_type(4)));
typedef short bf16x8  __attribute__((ext_vector_type(8)));
typedef unsigned short u16x8 __attribute__((ext_vector_type(8)));

#define N_ROWS 32768
#define F_DIM  32
#define U_DIM  64
#define RPB    16
#define NTHR   256
#define NBLK   (N_ROWS / RPB)   // 2048

// ---- LDS layout (total 19968 B) ----
#define X_OFF   0        // f32[16][36] x tile                      (2304)
#define WT_OFF  2304     // u16[16][40] softmax weights bf16        (1280)
#define PW_OFF  3584     // phase A: f32[2][1024] weight stage (8192)
                         // phase B: vst f32[4][576] (9216)
                         // finale : cmb f32[4][1024] (16384)
#define VA_OFF  11776    // f32[6][32] phase-A vectors              (768)
#define HX_OFF  12544    // f32[16][36] phase-A hidden              (2304)
#define SMEM_BYTES 19968

__device__ __forceinline__ unsigned short bfu(float x) {
  union { __hip_bfloat16 h; unsigned short u; } c;
  c.h = __float2bfloat16(x);
  return c.u;
}
__device__ __forceinline__ float bf2f(unsigned short u) {
  union { float f; unsigned v; } c; c.v = ((unsigned)u) << 16; return c.f;
}

// =====================================================================
// prep:
//  m=0: W2 as A-fragments for transposed GEMM1:
//       chunk c = nt*128+kt*64+lane ; val[j] = W2[f][8g+32kt+j][lr+16nt]
//  m=1,2: Wg1/Wg2 as B-fragments with custom k-order:
//       val[j] = W[f][4g+(j&3)+16*(j>>2)+32kt][lr+16nt]
//  vect[f][576] = [W1(64) | b1(64) | b2(64) | Q: (bg1,bg2,Wp,bp)[u] (256) |
//                  G: (gamma,beta)[u] (128)]
// =====================================================================
__global__ __launch_bounds__(256) void vsn_prep(
    const float* __restrict__ W2,  const float* __restrict__ Wg1, const float* __restrict__ Wg2,
    const float* __restrict__ W1,  const float* __restrict__ b1,  const float* __restrict__ b2,
    const float* __restrict__ bg1, const float* __restrict__ bg2,
    const float* __restrict__ Wp,  const float* __restrict__ bp,
    const float* __restrict__ gamma_, const float* __restrict__ beta_,
    unsigned short* __restrict__ wtg, float* __restrict__ vect)
{
  const int t = threadIdx.x, blk = blockIdx.x;
  if (blk < 192) {
    const int m = blk >> 6;              // 0..2
    const int f = (blk >> 1) & 31;
    const int half = blk & 1;
    const float* src = (m == 0) ? W2 : (m == 1) ? Wg1 : Wg2;
    src += f * 4096;
    const int c  = half * 256 + t;       // chunk 0..511
    const int nt = c >> 7;
    const int rr = c & 127;
    const int kt = rr >> 6;
    const int ln = rr & 63;
    const int g  = ln >> 4, lrr = ln & 15;
    const int uo = lrr + 16 * nt;
    u16x8 tmp;
    if (m == 0) {
      #pragma unroll
      for (int j = 0; j < 8; ++j)
        tmp[j] = bfu(src[(8 * g + 32 * kt + j) * 64 + uo]);
    } else {
      #pragma unroll
      for (int j = 0; j < 8; ++j)
        tmp[j] = bfu(src[(4 * g + (j & 3) + 16 * (j >> 2) + 32 * kt) * 64 + uo]);
    }
    *(u16x8*)(wtg + ((size_t)(m * 32 + f) * 512 + c) * 8) = tmp;
  } else {
    const int h = blk - 192;             // 0..1
    for (int i = h * 1024 + t; i < (h + 1) * 1024; i += 256) {
      const int f = i >> 6, u = i & 63;
      float* vf = vect + f * 576;
      vf[u]              = W1[i];
      vf[64 + u]         = b1[i];
      vf[128 + u]        = b2[i];
      vf[192 + u * 4 + 0] = bg1[i];
      vf[192 + u * 4 + 1] = bg2[i];
      vf[192 + u * 4 + 2] = Wp[i];
      vf[192 + u * 4 + 3] = bp[i];
      vf[448 + u * 2 + 0] = gamma_[i];
      vf[448 + u * 2 + 1] = beta_[i];
    }
  }
}

// =====================================================================
// main fused kernel
// =====================================================================
__global__ __launch_bounds__(NTHR, 4) void vsn_main(
    const float* __restrict__ x,
    const unsigned short* __restrict__ wtg,
    const float* __restrict__ vect,
    const float* __restrict__ w1w, const float* __restrict__ w2w,
    const float* __restrict__ wg1w, const float* __restrict__ wg2w,
    const float* __restrict__ b1w, const float* __restrict__ b2w,
    const float* __restrict__ bg1w, const float* __restrict__ bg2w,
    const float* __restrict__ gammaw, const float* __restrict__ betaw,
    float* __restrict__ out, float* __restrict__ wout)
{
  __shared__ __align__(16) char smem[SMEM_BYTES];
  const int t  = threadIdx.x;
  const int r0 = blockIdx.x * RPB;

  float* xt  = (float*)(smem + X_OFF);                      // [16][36] f32
  unsigned short* wtlb = (unsigned short*)(smem + WT_OFF);  // [16][40] bf16
  float* wA  = (float*)(smem + PW_OFF);                     // phase A stage
  float* vAl = (float*)(smem + VA_OFF);
  float* hex = (float*)(smem + HX_OFF);

  const int wid  = t >> 6;            // wave 0..3 -> f-quarter
  const int lane = t & 63;
  const int lr   = lane & 15;
  const int lg   = lane >> 4;
  const int fbase = wid * 8;

  // ---- stage x tile: 16 rows x 32 f = 128 f4 ----
  if (t < 128) {
    f4 v = ((const f4*)(x + (size_t)r0 * F_DIM))[t];
    *((f4*)(xt + (t >> 3) * 36 + ((t & 7) << 2))) = v;
  }

  // ---- prefetch f=fbase vect into regs (held through phase A) ----
  const f4* vect4 = (const f4*)vect;
  f4 rv0 = vect4[fbase * 144 + lane];
  f4 rv1 = vect4[fbase * 144 + 64 + lane];
  f4 rv2 = {};
  if (lane < 16) rv2 = vect4[fbase * 144 + 128 + lane];

  // ---- stage phase-A weights: w1w, w2w ----
  #pragma unroll
  for (int i = 0; i < 2; ++i) {
    int i4 = t + i * NTHR;                   // 0..511
    int m = i4 >> 8, off = (i4 & 255) << 2;
    const float* src = m ? w2w : w1w;
    *(f4*)(wA + m * 1024 + off) = *((const f4*)(src + off));
  }
  if (t < 48) {
    int m = t >> 3, off = (t & 7) << 2;
    const float* src = (m==0)?b1w:(m==1)?b2w:(m==2)?bg1w:(m==3)?bg2w:(m==4)?gammaw:betaw;
    *(f4*)(vAl + m * 32 + off) = *((const f4*)(src + off));
  }
  __syncthreads();

  // ================= PHASE A : weights GRN + softmax =================
  {
    const int ar = t >> 4;        // row 0..15
    const int g0 = (t & 15) << 1; // 2 output cols

    // stage 1: h1 = elu(x @ w1w + b1w)
    f2 hacc = { vAl[g0], vAl[g0 + 1] };
    #pragma unroll
    for (int ff = 0; ff < 32; ++ff) {
      float xv = xt[ar * 36 + ff];
      f2 w0 = *(const f2*)(wA + ff * 32 + g0);
      hacc.x += xv * w0.x; hacc.y += xv * w0.y;
    }
    hacc.x = hacc.x > 0.f ? hacc.x : (__expf(hacc.x) - 1.f);
    hacc.y = hacc.y > 0.f ? hacc.y : (__expf(hacc.y) - 1.f);
    *(f2*)(hex + ar * 36 + g0) = hacc;
    __syncthreads();

    // stage 2: h2 = h1 @ w2w + b2w
    f2 h2acc = { vAl[32 + g0], vAl[32 + g0 + 1] };
    #pragma unroll
    for (int ff = 0; ff < 32; ++ff) {
      float hv = hex[ar * 36 + ff];
      f2 w0 = *(const f2*)(wA + 1024 + ff * 32 + g0);
      h2acc.x += hv * w0.x; h2acc.y += hv * w0.y;
    }
    __syncthreads();   // h1 reads done; wA(w1w/w2w) reads done
    *(f2*)(hex + ar * 36 + g0) = h2acc;
    // restage wg1w, wg2w over wA
    #pragma unroll
    for (int i = 0; i < 2; ++i) {
      int i4 = t + i * NTHR;
      int m = i4 >> 8, off = (i4 & 255) << 2;
      const float* src = m ? wg2w : wg1w;
      *(f4*)(wA + m * 1024 + off) = *((const f4*)(src + off));
    }
    __syncthreads();

    // stage 3: GLU
    f2 aacc = { vAl[64 + g0], vAl[64 + g0 + 1] };
    f2 bacc = { vAl[96 + g0], vAl[96 + g0 + 1] };
    #pragma unroll
    for (int ff = 0; ff < 32; ++ff) {
      float hv = hex[ar * 36 + ff];
      f2 wa0 = *(const f2*)(wA + ff * 32 + g0);
      f2 wb0 = *(const f2*)(wA + 1024 + ff * 32 + g0);
      aacc.x += hv * wa0.x; aacc.y += hv * wa0.y;
      bacc.x += hv * wb0.x; bacc.y += hv * wb0.y;
    }
    f2 zz;
    {
      float sgx = __builtin_amdgcn_rcpf(1.f + __expf(-bacc.x));
      float sgy = __builtin_amdgcn_rcpf(1.f + __expf(-bacc.y));
      zz.x = aacc.x * sgx + xt[ar * 36 + g0];
      zz.y = aacc.y * sgy + xt[ar * 36 + g0 + 1];
    }
    __syncthreads();   // h2 reads done
    *(f2*)(hex + ar * 36 + g0) = zz;
    __syncthreads();

    // LN + softmax over F=32
    float s1 = 0.f, s2 = 0.f;
    #pragma unroll
    for (int ff = 0; ff < 32; ++ff) { float z = hex[ar * 36 + ff]; s1 += z; s2 += z * z; }
    float mA = s1 * 0.03125f;
    float vA = s2 * 0.03125f - mA * mA;
    float rsA = __builtin_amdgcn_rsqf(vA + 1e-3f);
    float mx = -1e30f;
    #pragma unroll
    for (int ff = 0; ff < 32; ++ff) {
      float y = (hex[ar * 36 + ff] - mA) * rsA * vAl[128 + ff] + vAl[160 + ff];
      mx = fmaxf(mx, y);
    }
    float es = 0.f;
    #pragma unroll
    for (int ff = 0; ff < 32; ++ff) {
      float y = (hex[ar * 36 + ff] - mA) * rsA * vAl[128 + ff] + vAl[160 + ff];
      es += __expf(y - mx);
    }
    float inv = __builtin_amdgcn_rcpf(es);
    float w0 = __expf((hex[ar * 36 + g0] - mA) * rsA * vAl[128 + g0] + vAl[160 + g0] - mx) * inv;
    float w1_ = __expf((hex[ar * 36 + g0 + 1] - mA) * rsA * vAl[128 + g0 + 1] + vAl[160 + g0 + 1] - mx) * inv;
    unsigned wu = (unsigned)bfu(w0) | ((unsigned)bfu(w1_) << 16);
    *(unsigned*)(wtlb + ar * 40 + g0) = wu;
    *(f2*)(wout + (size_t)(r0 + ar) * 32 + g0) = (f2){w0, w1_};
    __syncthreads();   // phase A done; PW region free for vst
  }

  // ================= PHASE B : per-feature GRNs (MFMA, barrier-free) ====
  f4* vst4 = ((f4*)(smem + PW_OFF)) + wid * 144;   // wave-private 576 f32
  float* vsc = (float*)(smem + PW_OFF) + wid * 576;

  vst4[lane] = rv0; vst4[64 + lane] = rv1;
  if (lane < 16) vst4[128 + lane] = rv2;

  const bf16x8* wf = (const bf16x8*)wtg;

  f32x4 acc[4];
  #pragma unroll
  for (int nt = 0; nt < 4; ++nt) acc[nt] = (f32x4){0.f, 0.f, 0.f, 0.f};

  for (int i = 0; i < 8; ++i) {
    const int f = fbase + i;

    // ---- GEMM1 A-operand: W2^T fragments (8 coalesced 16B from L2) ----
    const int base0 = (0 * 32 + f) * 512 + lane;
    bf16x8 w2f[8];
    #pragma unroll
    for (int nt = 0; nt < 4; ++nt)
      #pragma unroll
      for (int kt = 0; kt < 2; ++kt)
        w2f[nt * 2 + kt] = wf[base0 + nt * 128 + kt * 64];

    // ---- h1 B-fragments (batch row = lr), rank-1 + ELU ----
    const float s_ = xt[lr * 36 + f];
    bf16x8 afr[2];
    #pragma unroll
    for (int kt = 0; kt < 2; ++kt) {
      const int u0 = 8 * lg + 32 * kt;
      f4 wa  = *(const f4*)(vsc + u0);
      f4 wb_ = *(const f4*)(vsc + u0 + 4);
      f4 ba  = *(const f4*)(vsc + 64 + u0);
      f4 bb_ = *(const f4*)(vsc + 64 + u0 + 4);
      bf16x8 af;
      #pragma unroll
      for (int j = 0; j < 4; ++j) {
        float h = s_ * wa[j] + ba[j];
        h = h > 0.f ? h : (__expf(h) - 1.f);
        af[j] = (short)bfu(h);
      }
      #pragma unroll
      for (int j = 0; j < 4; ++j) {
        float h = s_ * wb_[j] + bb_[j];
        h = h > 0.f ? h : (__expf(h) - 1.f);
        af[4 + j] = (short)bfu(h);
      }
      afr[kt] = af;
    }

    // ---- transposed GEMM1: c1[nt'] = h2^T block (rows=u, cols=batch) ----
    f32x4 c1[4];
    #pragma unroll
    for (int nt = 0; nt < 4; ++nt) {
      c1[nt] = (f32x4){0.f, 0.f, 0.f, 0.f};
      #pragma unroll
      for (int kt = 0; kt < 2; ++kt)
        c1[nt] = __builtin_amdgcn_mfma_f32_16x16x32_bf16(w2f[nt * 2 + kt], afr[kt], c1[nt], 0, 0, 0);
    }

    // ---- a2 fragments assembled in registers: lane holds its own row ----
    f4 b2q[4];
    #pragma unroll
    for (int kt = 0; kt < 2; ++kt)
      #pragma unroll
      for (int n2 = 0; n2 < 2; ++n2)
        b2q[n2 + 2 * kt] = *(const f4*)(vsc + 128 + 4 * lg + 16 * n2 + 32 * kt);
    bf16x8 a2[2];
    #pragma unroll
    for (int kt = 0; kt < 2; ++kt) {
      bf16x8 af;
      #pragma unroll
      for (int j = 0; j < 8; ++j) {
        const int q = (j >> 2) + 2 * kt;
        af[j] = (short)bfu(c1[q][j & 3] + b2q[q][j & 3]);
      }
      a2[kt] = af;
    }

    // ---- GEMM2a ----
    const int base1 = (1 * 32 + f) * 512 + lane;
    bf16x8 bfa[8];
    #pragma unroll
    for (int nt = 0; nt < 4; ++nt)
      #pragma unroll
      for (int kt = 0; kt < 2; ++kt)
        bfa[nt * 2 + kt] = wf[base1 + nt * 128 + kt * 64];
    f32x4 ca[4], cb[4];
    #pragma unroll
    for (int nt = 0; nt < 4; ++nt) {
      ca[nt] = (f32x4){0.f,0.f,0.f,0.f};
      #pragma unroll
      for (int kt = 0; kt < 2; ++kt)
        ca[nt] = __builtin_amdgcn_mfma_f32_16x16x32_bf16(a2[kt], bfa[nt * 2 + kt], ca[nt], 0, 0, 0);
    }

    // ---- GEMM2b ----
    const int base2 = (2 * 32 + f) * 512 + lane;
    bf16x8 bfb[8];
    #pragma unroll
    for (int nt = 0; nt < 4; ++nt)
      #pragma unroll
      for (int kt = 0; kt < 2; ++kt)
        bfb[nt * 2 + kt] = wf[base2 + nt * 128 + kt * 64];
    #pragma unroll
    for (int nt = 0; nt < 4; ++nt) {
      cb[nt] = (f32x4){0.f,0.f,0.f,0.f};
      #pragma unroll
      for (int kt = 0; kt < 2; ++kt)
        cb[nt] = __builtin_amdgcn_mfma_f32_16x16x32_bf16(a2[kt], bfb[nt * 2 + kt], cb[nt], 0, 0, 0);
    }

    // ---- prefetch vect f+1 ----
    if (i < 7) {
      rv0 = vect4[(f + 1) * 144 + lane];
      rv1 = vect4[(f + 1) * 144 + 64 + lane];
      if (lane < 16) rv2 = vect4[(f + 1) * 144 + 128 + lane];
    }

    // ---- epilogue: GLU + residual + LN + weighted accumulate ----
    float xr[4], wr[4];
    #pragma unroll
    for (int rg = 0; rg < 4; ++rg) {
      const int rl = 4 * lg + rg;
      xr[rg] = xt[rl * 36 + f];
      wr[rg] = bf2f(wtlb[rl * 40 + f]);
    }
    float zf[4][4];
    float s1[4] = {0.f,0.f,0.f,0.f}, s2[4] = {0.f,0.f,0.f,0.f};
    #pragma unroll
    for (int nt = 0; nt < 4; ++nt) {
      const int u = lr + 16 * nt;
      f4 Q = *(const f4*)(vsc + 192 + u * 4);   // bg1, bg2, Wp, bp
      #pragma unroll
      for (int rg = 0; rg < 4; ++rg) {
        float a = ca[nt][rg] + Q[0];
        float b = cb[nt][rg] + Q[1];
        float sg = __builtin_amdgcn_rcpf(1.f + __expf(-b));
        float z = a * sg + (xr[rg] * Q[2] + Q[3]);
        zf[nt][rg] = z;
        s1[rg] += z;
        s2[rg] += z * z;
      }
    }
    #pragma unroll
    for (int rg = 0; rg < 4; ++rg) {
      #pragma unroll
      for (int m = 1; m < 16; m <<= 1) {
        s1[rg] += __shfl_xor(s1[rg], m, 64);
        s2[rg] += __shfl_xor(s2[rg], m, 64);
      }
    }
    float rswr[4], nc2[4];
    #pragma unroll
    for (int rg = 0; rg < 4; ++rg) {
      float mn = s1[rg] * 0.015625f;
      float var = s2[rg] * 0.015625f - mn * mn;
      float rs = __builtin_amdgcn_rsqf(var + 1e-3f);
      rswr[rg] = rs * wr[rg];
      nc2[rg]  = -mn * rswr[rg];
    }
    #pragma unroll
    for (int nt = 0; nt < 4; ++nt) {
      const int u = lr + 16 * nt;
      f2 G = *(const f2*)(vsc + 448 + u * 2);   // gamma, beta
      #pragma unroll
      for (int rg = 0; rg < 4; ++rg) {
        float tm = rswr[rg] * zf[nt][rg] + nc2[rg];
        acc[nt][rg] += G.x * tm + G.y * wr[rg];
      }
    }

    // ---- write f+1 vect to wave-private LDS (in-order DS, no barrier) ----
    if (i < 7) {
      vst4[lane] = rv0; vst4[64 + lane] = rv1;
      if (lane < 16) vst4[128 + lane] = rv2;
    }
  }

  // ---- combine the 4 f-quarters and store ----
  __syncthreads();    // all vst reads done; PW region free for cmb
  float* cmb = (float*)(smem + PW_OFF);
  #pragma unroll
  for (int nt = 0; nt < 4; ++nt)
    #pragma unroll
    for (int rg = 0; rg < 4; ++rg)
      cmb[wid * 1024 + (4 * lg + rg) * 64 + lr + 16 * nt] = acc[nt][rg];
  __syncthreads();
  {
    const f4* cmb4 = (const f4*)cmb;
    f4 o = cmb4[t] + cmb4[256 + t] + cmb4[512 + t] + cmb4[768 + t];
    ((f4*)(out + (size_t)r0 * U_DIM))[t] = o;
  }
}

// =====================================================================
extern "C" void kernel_launch(void* const* d_in, const int* in_sizes, int n_in,
                              void* d_out, int out_size, void* d_ws, size_t ws_size,
                              hipStream_t stream)
{
  (void)in_sizes; (void)n_in; (void)out_size; (void)ws_size;
  const float* x    = (const float*)d_in[0];
  const float* W1   = (const float*)d_in[1];
  const float* b1   = (const float*)d_in[2];
  const float* W2   = (const float*)d_in[3];
  const float* b2   = (const float*)d_in[4];
  const float* Wg1  = (const float*)d_in[5];
  const float* bg1  = (const float*)d_in[6];
  const float* Wg2  = (const float*)d_in[7];
  const float* bg2  = (const float*)d_in[8];
  const float* Wp   = (const float*)d_in[9];
  const float* bp   = (const float*)d_in[10];
  const float* gm   = (const float*)d_in[11];
  const float* bt   = (const float*)d_in[12];
  const float* w1w  = (const float*)d_in[13];
  const float* b1w  = (const float*)d_in[14];
  const float* w2w  = (const float*)d_in[15];
  const float* b2w  = (const float*)d_in[16];
  const float* wg1w = (const float*)d_in[17];
  const float* bg1w = (const float*)d_in[18];
  const float* wg2w = (const float*)d_in[19];
  const float* bg2w = (const float*)d_in[20];
  const float* gmw  = (const float*)d_in[21];
  const float* btw  = (const float*)d_in[22];

  unsigned short* wtg = (unsigned short*)d_ws;             // 786432 B
  float* vect = (float*)((char*)d_ws + 786432);            // 73728 B

  float* out  = (float*)d_out;
  float* wout = out + (size_t)N_ROWS * U_DIM;

  vsn_prep<<<194, 256, 0, stream>>>(W2, Wg1, Wg2, W1, b1, b2, bg1, bg2, Wp, bp, gm, bt, wtg, vect);
  vsn_main<<<NBLK, NTHR, 0, stream>>>(x, wtg, vect, w1w, w2w, wg1w, wg2w,
                                      b1w, b2w, bg1w, bg2w, gmw, btw, out, wout);
}